// Round 10
// baseline (118.395 us; speedup 1.0000x reference)
//
#include <hip/hip_runtime.h>
#include <hip/hip_bf16.h>

#define TB 8
#define TT 4096
#define TC 1024
#define THS 128

typedef __bf16 bf16;
typedef __attribute__((ext_vector_type(8))) __bf16 bf16x8;
typedef __attribute__((ext_vector_type(2))) __bf16 bf16x2;
typedef __attribute__((ext_vector_type(4))) float f32x4;
typedef __attribute__((ext_vector_type(16))) float f32x16;

__device__ __forceinline__ unsigned pkbf(float a, float b) {
    bf16x2 t = { (bf16)a, (bf16)b };
    return __builtin_bit_cast(unsigned, t);
}

__device__ __forceinline__ void gload16(const void* g, void* l) {
    __builtin_amdgcn_global_load_lds(
        (const __attribute__((address_space(1))) void*)g,
        (__attribute__((address_space(3))) void*)l, 16, 0, 0);
}

// ---- W cast+transpose via LDS tile: Wt[w][n][k] = bf16(W_w[k][n]) ----
__global__ __launch_bounds__(256) void wt_kernel(const float* __restrict__ Wq,
                                                 const float* __restrict__ Wk,
                                                 const float* __restrict__ Wv,
                                                 bf16* __restrict__ Wt) {
    __shared__ float tile[64][65];
    const int tid = threadIdx.x;
    const int idx = blockIdx.x;                  // 96 blocks: w*32 + kt*2 + ntb
    const int w = idx >> 5;
    const int kt = (idx & 31) >> 1, ntb = idx & 1;
    const int k0 = kt * 64, n0 = ntb * 64;
    const float* W = (w == 0) ? Wq : (w == 1) ? Wk : Wv;
    #pragma unroll
    for (int i = 0; i < 4; i++) {
        int r = (tid >> 4) + i * 16;
        int c4 = (tid & 15) * 4;
        float4 x4 = *reinterpret_cast<const float4*>(&W[(long)(k0 + r) * 128 + n0 + c4]);
        tile[r][c4 + 0] = x4.x; tile[r][c4 + 1] = x4.y;
        tile[r][c4 + 2] = x4.z; tile[r][c4 + 3] = x4.w;
    }
    __syncthreads();
    const int n = tid >> 2, kk = (tid & 3) * 16;
    bf16 o[16];
    #pragma unroll
    for (int j = 0; j < 16; j++) o[j] = (bf16)tile[kk + j][n];
    bf16* dst = &Wt[(long)((w << 7) + n0 + n) * 1024 + k0 + kk];
    *reinterpret_cast<bf16x8*>(dst)     = *reinterpret_cast<bf16x8*>(&o[0]);
    *reinterpret_cast<bf16x8*>(dst + 8) = *reinterpret_cast<bf16x8*>(&o[8]);
}

// ---- fused QKV projection, rebuilt on the attn R9 schedule ----
// 256 blocks x 512 threads: M-tile 128 rows, N=384 cols; 8 waves = 2 row-segs x 4
// col-segs (wave tile 64x96). BK=64 -> 16 steps. x tile [128][64] f32 double-buffered
// (2x32KB, stage-ahead-2: HBM latency hidden across 2 iterations); W tile [384][64]
// bf16 single-buffered (48KB, L2-resident, 1-iteration hiding). Counted vmcnt(4) at
// loop top (drains x(s)+W(s), keeps x(s+1)); vmcnt(0) only at the final step.
// All staging via global_load_lds with XOR-pre-swizzled sources (rule #21).
__global__ __launch_bounds__(512, 2) void qkv_kernel(const float* __restrict__ x,
                                                     const bf16* __restrict__ Wt,
                                                     bf16* __restrict__ Q,
                                                     bf16* __restrict__ K,
                                                     bf16* __restrict__ V) {
    __shared__ __align__(1024) char smem[114688];    // x dbuf @0/32K, W @64K (48KB)
    const int tid = threadIdx.x;
    const int wave = tid >> 6, lane = tid & 63;
    const int lr = lane & 15, g = lane >> 4;
    const int qs = wave >> 2, ns = wave & 3;
    const long row0 = (long)blockIdx.x * 128;

    int xOff[4], xL[4];                              // x: 32KB, rows 256B, swz256
    #pragma unroll
    for (int i = 0; i < 4; i++) {
        int D = wave * 4096 + i * 1024 + lane * 16;
        int r = D >> 8, c = D & 255;
        xOff[i] = r * 4096 + (c ^ (((r & 7) << 4) ^ (((r >> 3) & 1) << 7)));
        xL[i] = wave * 4096 + i * 1024;
    }
    int wOff[6], wL[6];                              // W: 48KB, rows 128B, swz128
    #pragma unroll
    for (int i = 0; i < 6; i++) {
        int D = wave * 6144 + i * 1024 + lane * 16;
        int n = D >> 7, c = D & 127;
        wOff[i] = n * 2048 + (c ^ ((n & 7) << 4));
        wL[i] = wave * 6144 + i * 1024;
    }
    const char* xb = (const char*)x + row0 * 4096;
    const char* wb = (const char*)Wt;

    f32x4 acc[4][6] = {};

    {   // prologue: x(0), W(0), x(1)  (issue order matters for counted waits)
        #pragma unroll
        for (int i = 0; i < 4; i++) gload16(xb + xOff[i], smem + xL[i]);
        #pragma unroll
        for (int i = 0; i < 6; i++) gload16(wb + wOff[i], smem + 65536 + wL[i]);
        #pragma unroll
        for (int i = 0; i < 4; i++) gload16(xb + 256 + xOff[i], smem + 32768 + xL[i]);
    }

    #pragma unroll 1
    for (int s = 0; s < 16; s++) {
        if (s < 15) asm volatile("s_waitcnt vmcnt(4)" ::: "memory");   // drain x(s),W(s); keep x(s+1)
        else        asm volatile("s_waitcnt vmcnt(0)" ::: "memory");
        __builtin_amdgcn_s_barrier();

        const char* xp = smem + (s & 1) * 32768;
        const char* wp = smem + 65536;
        bf16x8 a[4][2];
        #pragma unroll
        for (int ar = 0; ar < 4; ar++) {             // A-frags: f32 LDS -> bf16 regs
            const int r = qs * 64 + ar * 16 + lr;
            const int rs = ((r & 7) << 4) ^ (((r >> 3) & 1) << 7);
            #pragma unroll
            for (int ks = 0; ks < 2; ks++) {
                f32x4 lo  = *reinterpret_cast<const f32x4*>(xp + r * 256 + ((ks * 128 + g * 32) ^ rs));
                f32x4 hi4 = *reinterpret_cast<const f32x4*>(xp + r * 256 + ((ks * 128 + g * 32 + 16) ^ rs));
                uint4 u;
                u.x = pkbf(lo[0], lo[1]);  u.y = pkbf(lo[2], lo[3]);
                u.z = pkbf(hi4[0], hi4[1]); u.w = pkbf(hi4[2], hi4[3]);
                a[ar][ks] = __builtin_bit_cast(bf16x8, u);
            }
        }
        __builtin_amdgcn_s_setprio(1);
        #pragma unroll
        for (int nt = 0; nt < 6; nt++) {
            const int n = ns * 96 + nt * 16 + lr;
            const int nsw = (n & 7) << 4;
            #pragma unroll
            for (int ks = 0; ks < 2; ks++) {
                bf16x8 bfr = *reinterpret_cast<const bf16x8*>(wp + n * 128 + ((ks * 64 + g * 16) ^ nsw));
                #pragma unroll
                for (int ar = 0; ar < 4; ar++)
                    acc[ar][nt] = __builtin_amdgcn_mfma_f32_16x16x32_bf16(a[ar][ks], bfr, acc[ar][nt], 0, 0, 0);
            }
        }
        __builtin_amdgcn_s_setprio(0);
        __builtin_amdgcn_s_barrier();                // all waves done with x(s) buf + W

        if (s + 1 < 16) {                            // stage W(s+1) then x(s+2)
            #pragma unroll
            for (int i = 0; i < 6; i++)
                gload16(wb + (s + 1) * 128 + wOff[i], smem + 65536 + wL[i]);
        }
        if (s + 2 < 16) {
            #pragma unroll
            for (int i = 0; i < 4; i++)
                gload16(xb + (s + 2) * 256 + xOff[i], smem + (s & 1) * 32768 + xL[i]);
        }
    }

    const float qscale = 0.08838834764831845f;       // 128^-0.5
    bf16* outs[3] = {Q, K, V};
    #pragma unroll
    for (int nt = 0; nt < 6; nt++) {
        const int col = ns * 96 + nt * 16 + lr;
        const int w = col >> 7, d = col & 127;
        #pragma unroll
        for (int ar = 0; ar < 4; ar++)
            #pragma unroll
            for (int r = 0; r < 4; r++) {
                float val = acc[ar][nt][r];
                if (w == 0) val *= qscale;
                long row = row0 + qs * 64 + ar * 16 + g * 4 + r;
                outs[w][row * 128 + d] = (bf16)val;
            }
    }
}

// ---- V transpose, tile-major: Vtt[b][t64][d][kv64] (each tile contiguous 16KB) ----
__global__ __launch_bounds__(256) void vtrans_kernel(const bf16* __restrict__ V,
                                                     bf16* __restrict__ Vtt) {
    __shared__ __align__(16) bf16 tile[64][136];
    const int tid = threadIdx.x;
    const int b = blockIdx.y;
    const int tt = blockIdx.x;
    const long ibase = ((long)b * TT + tt * 64) * 128;
    #pragma unroll
    for (int i = 0; i < 4; i++) {
        int slot = tid + 256 * i;
        int r = slot >> 4, c8 = (slot & 15) * 8;
        *reinterpret_cast<bf16x8*>(&tile[r][c8]) =
            *reinterpret_cast<const bf16x8*>(&V[ibase + r * 128 + c8]);
    }
    __syncthreads();
    #pragma unroll
    for (int i = 0; i < 4; i++) {
        int slot = tid + 256 * i;
        int d = slot >> 3, t8 = (slot & 7) * 8;
        bf16x8 v;
        #pragma unroll
        for (int j = 0; j < 8; j++) v[j] = tile[t8 + j][d];
        *reinterpret_cast<bf16x8*>(&Vtt[(((long)b * 64 + tt) * 128 + d) * 64 + t8]) = v;
    }
}

// ---- causal flash attention (unchanged from R9) ----
__global__ __launch_bounds__(512, 2) void attn_kernel(const bf16* __restrict__ Q,
                                                      const bf16* __restrict__ K,
                                                      const bf16* __restrict__ Vtt,
                                                      float* __restrict__ out) {
    __shared__ __align__(1024) char smem[131072];        // kbuf[2]@0/32K, vbuf[2]@64K/96K
    __shared__ float mlb[6 * 64];
    const int tid = threadIdx.x;
    const int wave = tid >> 6, lane = tid & 63;
    const int c = lane & 31, hi = lane >> 5;
    const int qs = wave >> 2, kvq = wave & 3;
    const int kswz = ((c & 7) << 4) ^ (((c >> 3) & 1) << 7);
    const int vswz = (c & 7) << 4;
    const int v = blockIdx.x >> 3, b = blockIdx.x & 7;   // batch pinned to XCD
    const long base = (long)b * TT * 128;
    const char* Kb = (const char*)(K + base);
    const char* Vb = (const char*)Vtt + (long)b * (64 * 16384);

    int kOff[4], vOff[4], lOff[4];
    #pragma unroll
    for (int i = 0; i < 4; i++) {
        int D = wave * 4096 + i * 1024 + lane * 16;      // linear dest byte in 32KB
        kOff[i] = (D & ~255) | ((D & 255) ^ (((D >> 8) & 7) << 4) ^ (((D >> 11) & 1) << 7));
        vOff[i] = (D & ~127) | ((D & 127) ^ (((D >> 7) & 7) << 4));
        lOff[i] = wave * 4096 + i * 1024;                // HW adds lane*16
    }

    #pragma unroll 1
    for (int ph = 0; ph < 2; ph++) {
        const int qt = ph ? 63 - v : v;
        const int nIt = (qt + 2) >> 1;                   // ceil((qt+1)/2) KVB=128 tiles
        const int q0w = qt * 64 + qs * 32;
        const int qa = q0w + c;

        bf16x8 qf[8];
        #pragma unroll
        for (int dw = 0; dw < 8; dw++)
            qf[dw] = *reinterpret_cast<const bf16x8*>(&Q[base + (long)qa * 128 + dw * 16 + hi * 8]);

        f32x16 O[4] = {};
        float m = -__builtin_inff(), l = 0.f;

        {   // prologue: stage tiles 0 (and 1) -> stage-ahead-2
            #pragma unroll
            for (int i = 0; i < 4; i++) {
                gload16(Kb + kOff[i], smem + lOff[i]);
                gload16(Vb + vOff[i], smem + 65536 + lOff[i]);
            }
            if (nIt > 1) {
                #pragma unroll
                for (int i = 0; i < 4; i++) {
                    gload16(Kb + 32768 + kOff[i], smem + 32768 + lOff[i]);
                    gload16(Vb + 32768 + vOff[i], smem + 98304 + lOff[i]);
                }
            }
        }

        #pragma unroll 1
        for (int it = 0; it < nIt; it++) {
            const int bi = it & 1;
            char* kBuf = smem + bi * 32768;              // runtime-indexed (no const-init LDS ptr)
            char* vBuf = smem + 65536 + bi * 32768;
            if (it + 1 < nIt) asm volatile("s_waitcnt vmcnt(8)" ::: "memory");
            else              asm volatile("s_waitcnt vmcnt(0)" ::: "memory");
            __builtin_amdgcn_s_barrier();                // tile it visible to all waves

            const int kv0 = it * 128 + kvq * 32;
            if (kv0 <= q0w) {                            // 32-aligned => no empty q-rows
                const char* kb = kBuf + kvq * 8192;
                const char* vb = vBuf + (kvq >> 1) * 16384;
                const int vcol0 = (kvq & 1) * 64;        // byte offset of wave's 32 kv
                f32x16 S = {};
                __builtin_amdgcn_s_setprio(1);
                #pragma unroll
                for (int dw = 0; dw < 8; dw++) {         // S^T = K Q^T
                    bf16x8 kf = *reinterpret_cast<const bf16x8*>(
                        kb + c * 256 + ((dw * 32 + hi * 16) ^ kswz));
                    S = __builtin_amdgcn_mfma_f32_32x32x16_bf16(kf, qf[dw], S, 0, 0, 0);
                }
                __builtin_amdgcn_s_setprio(0);
                if (kv0 == q0w) {                        // diagonal tile: causal mask
                    #pragma unroll
                    for (int i = 0; i < 16; i++) {
                        int kvr = kv0 + (i & 3) + 8 * (i >> 2) + 4 * hi;
                        if (kvr > qa) S[i] = -__builtin_inff();
                    }
                }
                float t8[8];
                #pragma unroll
                for (int i = 0; i < 8; i++) t8[i] = fmaxf(S[i], S[i + 8]);
                float t4a = fmaxf(t8[0], t8[4]), t4b = fmaxf(t8[1], t8[5]);
                float t4c = fmaxf(t8[2], t8[6]), t4d = fmaxf(t8[3], t8[7]);
                float pm = fmaxf(fmaxf(t4a, t4b), fmaxf(t4c, t4d));
                pm = fmaxf(pm, __shfl_xor(pm, 32, 64));  // partner half (other 16 kv regs)
                if (!__all(pm - m <= 8.0f)) {            // defer-max
                    float mn = fmaxf(m, pm);
                    float fr = __expf(m - mn);
                    #pragma unroll
                    for (int dt = 0; dt < 4; dt++) O[dt] = O[dt] * fr;
                    l *= fr;
                    m = mn;
                }
                #pragma unroll
                for (int i = 0; i < 16; i++) S[i] = __expf(S[i] - m);
                float s8[8];
                #pragma unroll
                for (int i = 0; i < 8; i++) s8[i] = S[i] + S[i + 8];
                l += ((s8[0] + s8[4]) + (s8[1] + s8[5])) + ((s8[2] + s8[6]) + (s8[3] + s8[7]));

                bf16x8 pf[2];                            // P -> B-frags, sel-trick exchange
                #pragma unroll
                for (int wl = 0; wl < 2; wl++) {
                    const int i0 = 8 * wl;
                    unsigned L0 = pkbf(S[i0 + 0], S[i0 + 1]);
                    unsigned L1 = pkbf(S[i0 + 2], S[i0 + 3]);
                    unsigned H0 = pkbf(S[i0 + 4], S[i0 + 5]);
                    unsigned H1 = pkbf(S[i0 + 6], S[i0 + 7]);
                    unsigned sel0 = hi ? L0 : H0;        // offer what partner needs
                    unsigned sel1 = hi ? L1 : H1;
                    unsigned x0 = __shfl_xor((int)sel0, 32, 64);
                    unsigned x1 = __shfl_xor((int)sel1, 32, 64);
                    uint4 f;
                    f.x = hi ? x0 : L0;
                    f.y = hi ? x1 : L1;
                    f.z = hi ? H0 : x0;
                    f.w = hi ? H1 : x1;
                    pf[wl] = __builtin_bit_cast(bf16x8, f);
                }
                __builtin_amdgcn_s_setprio(1);
                #pragma unroll
                for (int wl = 0; wl < 2; wl++)           // O^T += V^T P
                    #pragma unroll
                    for (int dt = 0; dt < 4; dt++) {
                        bf16x8 vf = *reinterpret_cast<const bf16x8*>(
                            vb + (dt * 32 + c) * 128 + ((vcol0 + wl * 32 + hi * 16) ^ vswz));
                        O[dt] = __builtin_amdgcn_mfma_f32_32x32x16_bf16(vf, pf[wl], O[dt], 0, 0, 0);
                    }
                __builtin_amdgcn_s_setprio(0);
            }
            __builtin_amdgcn_s_barrier();                // all waves done reading buf bi
            if (it + 2 < nIt) {                          // stage it+2 into freed buffer
                const char* Ks = Kb + (long)(it + 2) * 32768;
                const char* Vs = Vb + (long)(it + 2) * 32768;
                #pragma unroll
                for (int i = 0; i < 4; i++) {
                    gload16(Ks + kOff[i], kBuf + lOff[i]);
                    gload16(Vs + vOff[i], vBuf + lOff[i]);
                }
            }
        }

        l += __shfl_xor(l, 32, 64);                      // combine partner kv-reg halves

        if (kvq != 0) {                                  // quarters 1..3 publish partials
            const int sl = qs * 3 + (kvq - 1);
            char* om = smem + sl * 16384;
            #pragma unroll
            for (int dt = 0; dt < 4; dt++)
                #pragma unroll
                for (int g = 0; g < 4; g++) {
                    float4 w4 = { O[dt][4 * g + 0], O[dt][4 * g + 1],
                                  O[dt][4 * g + 2], O[dt][4 * g + 3] };
                    *reinterpret_cast<float4*>(
                        om + c * 512 + ((dt * 128 + g * 32 + hi * 16) ^ ((c & 7) << 4))) = w4;
                }
            if (hi == 0) { mlb[sl * 64 + c] = m; mlb[sl * 64 + 32 + c] = l; }
        }
        __syncthreads();
        if (kvq == 0) {                                  // quarter 0 merges + writes out
            float mq[3], lq[3];
            float mx = m;                                // kvq0 always has data (finite)
            #pragma unroll
            for (int p = 0; p < 3; p++) {
                const int sl = qs * 3 + p;
                mq[p] = mlb[sl * 64 + c];
                lq[p] = mlb[sl * 64 + 32 + c];
                mx = fmaxf(mx, mq[p]);
            }
            float f0 = __expf(m - mx);
            float lt = l * f0;
            float fq[3];
            #pragma unroll
            for (int p = 0; p < 3; p++) { fq[p] = __expf(mq[p] - mx); lt += lq[p] * fq[p]; }
            float linv = 1.0f / lt;
            #pragma unroll
            for (int dt = 0; dt < 4; dt++)
                #pragma unroll
                for (int g = 0; g < 4; g++) {
                    float4 r;
                    r.x = O[dt][4 * g + 0] * f0;
                    r.y = O[dt][4 * g + 1] * f0;
                    r.z = O[dt][4 * g + 2] * f0;
                    r.w = O[dt][4 * g + 3] * f0;
                    #pragma unroll
                    for (int p = 0; p < 3; p++) {
                        const char* om = smem + (qs * 3 + p) * 16384;
                        float4 o1 = *reinterpret_cast<const float4*>(
                            om + c * 512 + ((dt * 128 + g * 32 + hi * 16) ^ ((c & 7) << 4)));
                        r.x += o1.x * fq[p]; r.y += o1.y * fq[p];
                        r.z += o1.z * fq[p]; r.w += o1.w * fq[p];
                    }
                    r.x *= linv; r.y *= linv; r.z *= linv; r.w *= linv;
                    *reinterpret_cast<float4*>(
                        &out[base + (long)qa * 128 + dt * 32 + 8 * g + 4 * hi]) = r;
                }
        }
        __syncthreads();                                 // LDS safe before next phase stages
    }
}

extern "C" void kernel_launch(void* const* d_in, const int* in_sizes, int n_in,
                              void* d_out, int out_size, void* d_ws, size_t ws_size,
                              hipStream_t stream) {
    const float* x  = (const float*)d_in[0];
    const float* Wq = (const float*)d_in[1];
    const float* Wk = (const float*)d_in[2];
    const float* Wv = (const float*)d_in[3];
    float* out = (float*)d_out;
    bf16* Q   = (bf16*)d_ws;                      // [32768][128]
    bf16* K   = Q   + (size_t)32768 * 128;
    bf16* V   = K   + (size_t)32768 * 128;
    bf16* Wt  = V   + (size_t)32768 * 128;        // [3][128][1024]
    bf16* Vtt = Wt  + (size_t)3 * 128 * 1024;     // [8][64][128][64] tile-major
    wt_kernel<<<96, 256, 0, stream>>>(Wq, Wk, Wv, Wt);
    qkv_kernel<<<256, 512, 0, stream>>>(x, Wt, Q, K, V);
    vtrans_kernel<<<dim3(64, 8), 256, 0, stream>>>(V, Vtt);
    attn_kernel<<<256, 512, 0, stream>>>(Q, K, Vtt, out);
}

// Round 11
// 116.273 us; speedup vs baseline: 1.0183x; 1.0183x over previous
//
#include <hip/hip_runtime.h>
#include <hip/hip_bf16.h>

#define TB 8
#define TT 4096
#define TC 1024
#define THS 128

typedef __bf16 bf16;
typedef __attribute__((ext_vector_type(8))) __bf16 bf16x8;
typedef __attribute__((ext_vector_type(2))) __bf16 bf16x2;
typedef __attribute__((ext_vector_type(4))) float f32x4;
typedef __attribute__((ext_vector_type(16))) float f32x16;

__device__ __forceinline__ unsigned pkbf(float a, float b) {
    bf16x2 t = { (bf16)a, (bf16)b };
    return __builtin_bit_cast(unsigned, t);
}

__device__ __forceinline__ void gload16(const void* g, void* l) {
    __builtin_amdgcn_global_load_lds(
        (const __attribute__((address_space(1))) void*)g,
        (__attribute__((address_space(3))) void*)l, 16, 0, 0);
}

// ---- W cast+transpose via LDS tile: Wt[w][n][k] = bf16(W_w[k][n]) ----
__global__ __launch_bounds__(256) void wt_kernel(const float* __restrict__ Wq,
                                                 const float* __restrict__ Wk,
                                                 const float* __restrict__ Wv,
                                                 bf16* __restrict__ Wt) {
    __shared__ float tile[64][65];
    const int tid = threadIdx.x;
    const int idx = blockIdx.x;                  // 96 blocks: w*32 + kt*2 + ntb
    const int w = idx >> 5;
    const int kt = (idx & 31) >> 1, ntb = idx & 1;
    const int k0 = kt * 64, n0 = ntb * 64;
    const float* W = (w == 0) ? Wq : (w == 1) ? Wk : Wv;
    #pragma unroll
    for (int i = 0; i < 4; i++) {
        int r = (tid >> 4) + i * 16;
        int c4 = (tid & 15) * 4;
        float4 x4 = *reinterpret_cast<const float4*>(&W[(long)(k0 + r) * 128 + n0 + c4]);
        tile[r][c4 + 0] = x4.x; tile[r][c4 + 1] = x4.y;
        tile[r][c4 + 2] = x4.z; tile[r][c4 + 3] = x4.w;
    }
    __syncthreads();
    const int n = tid >> 2, kk = (tid & 3) * 16;
    bf16 o[16];
    #pragma unroll
    for (int j = 0; j < 16; j++) o[j] = (bf16)tile[kk + j][n];
    bf16* dst = &Wt[(long)((w << 7) + n0 + n) * 1024 + k0 + kk];
    *reinterpret_cast<bf16x8*>(dst)     = *reinterpret_cast<bf16x8*>(&o[0]);
    *reinterpret_cast<bf16x8*>(dst + 8) = *reinterpret_cast<bf16x8*>(&o[8]);
}

// ---- fused QKV projection, 2 blocks/CU for stall-filling ----
// 512 blocks x 512 threads: M-tile 64 rows, N=384; 8 waves = 2 row-segs x 4 col-segs
// (wave 32x96). BK=64 -> 16 steps. LDS 80KB = x dbuf 2x16KB + W 48KB -> 2 blocks/CU:
// while one block sits in vmcnt/barrier or W-L2 latency, the other issues MFMA/LDS
// (m114 wave-overlap -- the mechanism R10's 1-block/CU version lacked).
// Counted vmcnt(2) at loop top; vmcnt(0) only at last step. XOR-swizzled sources.
__global__ __launch_bounds__(512, 4) void qkv_kernel(const float* __restrict__ x,
                                                     const bf16* __restrict__ Wt,
                                                     bf16* __restrict__ Q,
                                                     bf16* __restrict__ K,
                                                     bf16* __restrict__ V) {
    __shared__ __align__(1024) char smem[81920];     // x dbuf @0/16K, W @32K (48KB)
    const int tid = threadIdx.x;
    const int wave = tid >> 6, lane = tid & 63;
    const int lr = lane & 15, g = lane >> 4;
    const int qs = wave >> 2, ns = wave & 3;
    const long row0 = (long)blockIdx.x * 64;

    int xOff[2], xL[2];                              // x: 16KB, rows 256B, swz256
    #pragma unroll
    for (int i = 0; i < 2; i++) {
        int D = wave * 2048 + i * 1024 + lane * 16;
        int r = D >> 8, c = D & 255;
        xOff[i] = r * 4096 + (c ^ (((r & 7) << 4) ^ (((r >> 3) & 1) << 7)));
        xL[i] = wave * 2048 + i * 1024;
    }
    int wOff[6], wL[6];                              // W: 48KB, rows 128B, swz128
    #pragma unroll
    for (int i = 0; i < 6; i++) {
        int D = wave * 6144 + i * 1024 + lane * 16;
        int n = D >> 7, c = D & 127;
        wOff[i] = n * 2048 + (c ^ ((n & 7) << 4));
        wL[i] = wave * 6144 + i * 1024;
    }
    const char* xb = (const char*)x + row0 * 4096;
    const char* wb = (const char*)Wt;

    f32x4 acc[2][6] = {};

    {   // prologue: x(0), W(0), x(1)
        #pragma unroll
        for (int i = 0; i < 2; i++) gload16(xb + xOff[i], smem + xL[i]);
        #pragma unroll
        for (int i = 0; i < 6; i++) gload16(wb + wOff[i], smem + 32768 + wL[i]);
        #pragma unroll
        for (int i = 0; i < 2; i++) gload16(xb + 256 + xOff[i], smem + 16384 + xL[i]);
    }

    #pragma unroll 1
    for (int s = 0; s < 16; s++) {
        if (s < 15) asm volatile("s_waitcnt vmcnt(2)" ::: "memory");   // drain x(s),W(s); keep x(s+1)
        else        asm volatile("s_waitcnt vmcnt(0)" ::: "memory");
        __builtin_amdgcn_s_barrier();

        const char* xp = smem + (s & 1) * 16384;
        const char* wp = smem + 32768;
        bf16x8 a[2][2];
        #pragma unroll
        for (int ar = 0; ar < 2; ar++) {             // A-frags: f32 LDS -> bf16 regs
            const int r = qs * 32 + ar * 16 + lr;
            const int rs = ((r & 7) << 4) ^ (((r >> 3) & 1) << 7);
            #pragma unroll
            for (int ks = 0; ks < 2; ks++) {
                f32x4 lo  = *reinterpret_cast<const f32x4*>(xp + r * 256 + ((ks * 128 + g * 32) ^ rs));
                f32x4 hi4 = *reinterpret_cast<const f32x4*>(xp + r * 256 + ((ks * 128 + g * 32 + 16) ^ rs));
                uint4 u;
                u.x = pkbf(lo[0], lo[1]);  u.y = pkbf(lo[2], lo[3]);
                u.z = pkbf(hi4[0], hi4[1]); u.w = pkbf(hi4[2], hi4[3]);
                a[ar][ks] = __builtin_bit_cast(bf16x8, u);
            }
        }
        __builtin_amdgcn_s_setprio(1);
        #pragma unroll
        for (int nt = 0; nt < 6; nt++) {
            const int n = ns * 96 + nt * 16 + lr;
            const int nsw = (n & 7) << 4;
            #pragma unroll
            for (int ks = 0; ks < 2; ks++) {
                bf16x8 bfr = *reinterpret_cast<const bf16x8*>(wp + n * 128 + ((ks * 64 + g * 16) ^ nsw));
                #pragma unroll
                for (int ar = 0; ar < 2; ar++)
                    acc[ar][nt] = __builtin_amdgcn_mfma_f32_16x16x32_bf16(a[ar][ks], bfr, acc[ar][nt], 0, 0, 0);
            }
        }
        __builtin_amdgcn_s_setprio(0);
        __builtin_amdgcn_s_barrier();                // all waves done with x(s) buf + W

        if (s + 1 < 16) {                            // stage W(s+1) then x(s+2)
            #pragma unroll
            for (int i = 0; i < 6; i++)
                gload16(wb + (s + 1) * 128 + wOff[i], smem + 32768 + wL[i]);
        }
        if (s + 2 < 16) {
            #pragma unroll
            for (int i = 0; i < 2; i++)
                gload16(xb + (s + 2) * 256 + xOff[i], smem + (s & 1) * 16384 + xL[i]);
        }
    }

    const float qscale = 0.08838834764831845f;       // 128^-0.5
    bf16* outs[3] = {Q, K, V};
    #pragma unroll
    for (int nt = 0; nt < 6; nt++) {
        const int col = ns * 96 + nt * 16 + lr;
        const int w = col >> 7, d = col & 127;
        #pragma unroll
        for (int ar = 0; ar < 2; ar++)
            #pragma unroll
            for (int r = 0; r < 4; r++) {
                float val = acc[ar][nt][r];
                if (w == 0) val *= qscale;
                long row = row0 + qs * 32 + ar * 16 + g * 4 + r;
                outs[w][row * 128 + d] = (bf16)val;
            }
    }
}

// ---- V transpose, tile-major: Vtt[b][t64][d][kv64] (each tile contiguous 16KB) ----
__global__ __launch_bounds__(256) void vtrans_kernel(const bf16* __restrict__ V,
                                                     bf16* __restrict__ Vtt) {
    __shared__ __align__(16) bf16 tile[64][136];
    const int tid = threadIdx.x;
    const int b = blockIdx.y;
    const int tt = blockIdx.x;
    const long ibase = ((long)b * TT + tt * 64) * 128;
    #pragma unroll
    for (int i = 0; i < 4; i++) {
        int slot = tid + 256 * i;
        int r = slot >> 4, c8 = (slot & 15) * 8;
        *reinterpret_cast<bf16x8*>(&tile[r][c8]) =
            *reinterpret_cast<const bf16x8*>(&V[ibase + r * 128 + c8]);
    }
    __syncthreads();
    #pragma unroll
    for (int i = 0; i < 4; i++) {
        int slot = tid + 256 * i;
        int d = slot >> 3, t8 = (slot & 7) * 8;
        bf16x8 v;
        #pragma unroll
        for (int j = 0; j < 8; j++) v[j] = tile[t8 + j][d];
        *reinterpret_cast<bf16x8*>(&Vtt[(((long)b * 64 + tt) * 128 + d) * 64 + t8]) = v;
    }
}

// ---- causal flash attention (unchanged from R9) ----
__global__ __launch_bounds__(512, 2) void attn_kernel(const bf16* __restrict__ Q,
                                                      const bf16* __restrict__ K,
                                                      const bf16* __restrict__ Vtt,
                                                      float* __restrict__ out) {
    __shared__ __align__(1024) char smem[131072];        // kbuf[2]@0/32K, vbuf[2]@64K/96K
    __shared__ float mlb[6 * 64];
    const int tid = threadIdx.x;
    const int wave = tid >> 6, lane = tid & 63;
    const int c = lane & 31, hi = lane >> 5;
    const int qs = wave >> 2, kvq = wave & 3;
    const int kswz = ((c & 7) << 4) ^ (((c >> 3) & 1) << 7);
    const int vswz = (c & 7) << 4;
    const int v = blockIdx.x >> 3, b = blockIdx.x & 7;   // batch pinned to XCD
    const long base = (long)b * TT * 128;
    const char* Kb = (const char*)(K + base);
    const char* Vb = (const char*)Vtt + (long)b * (64 * 16384);

    int kOff[4], vOff[4], lOff[4];
    #pragma unroll
    for (int i = 0; i < 4; i++) {
        int D = wave * 4096 + i * 1024 + lane * 16;      // linear dest byte in 32KB
        kOff[i] = (D & ~255) | ((D & 255) ^ (((D >> 8) & 7) << 4) ^ (((D >> 11) & 1) << 7));
        vOff[i] = (D & ~127) | ((D & 127) ^ (((D >> 7) & 7) << 4));
        lOff[i] = wave * 4096 + i * 1024;                // HW adds lane*16
    }

    #pragma unroll 1
    for (int ph = 0; ph < 2; ph++) {
        const int qt = ph ? 63 - v : v;
        const int nIt = (qt + 2) >> 1;                   // ceil((qt+1)/2) KVB=128 tiles
        const int q0w = qt * 64 + qs * 32;
        const int qa = q0w + c;

        bf16x8 qf[8];
        #pragma unroll
        for (int dw = 0; dw < 8; dw++)
            qf[dw] = *reinterpret_cast<const bf16x8*>(&Q[base + (long)qa * 128 + dw * 16 + hi * 8]);

        f32x16 O[4] = {};
        float m = -__builtin_inff(), l = 0.f;

        {   // prologue: stage tiles 0 (and 1) -> stage-ahead-2
            #pragma unroll
            for (int i = 0; i < 4; i++) {
                gload16(Kb + kOff[i], smem + lOff[i]);
                gload16(Vb + vOff[i], smem + 65536 + lOff[i]);
            }
            if (nIt > 1) {
                #pragma unroll
                for (int i = 0; i < 4; i++) {
                    gload16(Kb + 32768 + kOff[i], smem + 32768 + lOff[i]);
                    gload16(Vb + 32768 + vOff[i], smem + 98304 + lOff[i]);
                }
            }
        }

        #pragma unroll 1
        for (int it = 0; it < nIt; it++) {
            const int bi = it & 1;
            char* kBuf = smem + bi * 32768;              // runtime-indexed (no const-init LDS ptr)
            char* vBuf = smem + 65536 + bi * 32768;
            if (it + 1 < nIt) asm volatile("s_waitcnt vmcnt(8)" ::: "memory");
            else              asm volatile("s_waitcnt vmcnt(0)" ::: "memory");
            __builtin_amdgcn_s_barrier();                // tile it visible to all waves

            const int kv0 = it * 128 + kvq * 32;
            if (kv0 <= q0w) {                            // 32-aligned => no empty q-rows
                const char* kb = kBuf + kvq * 8192;
                const char* vb = vBuf + (kvq >> 1) * 16384;
                const int vcol0 = (kvq & 1) * 64;        // byte offset of wave's 32 kv
                f32x16 S = {};
                __builtin_amdgcn_s_setprio(1);
                #pragma unroll
                for (int dw = 0; dw < 8; dw++) {         // S^T = K Q^T
                    bf16x8 kf = *reinterpret_cast<const bf16x8*>(
                        kb + c * 256 + ((dw * 32 + hi * 16) ^ kswz));
                    S = __builtin_amdgcn_mfma_f32_32x32x16_bf16(kf, qf[dw], S, 0, 0, 0);
                }
                __builtin_amdgcn_s_setprio(0);
                if (kv0 == q0w) {                        // diagonal tile: causal mask
                    #pragma unroll
                    for (int i = 0; i < 16; i++) {
                        int kvr = kv0 + (i & 3) + 8 * (i >> 2) + 4 * hi;
                        if (kvr > qa) S[i] = -__builtin_inff();
                    }
                }
                float t8[8];
                #pragma unroll
                for (int i = 0; i < 8; i++) t8[i] = fmaxf(S[i], S[i + 8]);
                float t4a = fmaxf(t8[0], t8[4]), t4b = fmaxf(t8[1], t8[5]);
                float t4c = fmaxf(t8[2], t8[6]), t4d = fmaxf(t8[3], t8[7]);
                float pm = fmaxf(fmaxf(t4a, t4b), fmaxf(t4c, t4d));
                pm = fmaxf(pm, __shfl_xor(pm, 32, 64));  // partner half (other 16 kv regs)
                if (!__all(pm - m <= 8.0f)) {            // defer-max
                    float mn = fmaxf(m, pm);
                    float fr = __expf(m - mn);
                    #pragma unroll
                    for (int dt = 0; dt < 4; dt++) O[dt] = O[dt] * fr;
                    l *= fr;
                    m = mn;
                }
                #pragma unroll
                for (int i = 0; i < 16; i++) S[i] = __expf(S[i] - m);
                float s8[8];
                #pragma unroll
                for (int i = 0; i < 8; i++) s8[i] = S[i] + S[i + 8];
                l += ((s8[0] + s8[4]) + (s8[1] + s8[5])) + ((s8[2] + s8[6]) + (s8[3] + s8[7]));

                bf16x8 pf[2];                            // P -> B-frags, sel-trick exchange
                #pragma unroll
                for (int wl = 0; wl < 2; wl++) {
                    const int i0 = 8 * wl;
                    unsigned L0 = pkbf(S[i0 + 0], S[i0 + 1]);
                    unsigned L1 = pkbf(S[i0 + 2], S[i0 + 3]);
                    unsigned H0 = pkbf(S[i0 + 4], S[i0 + 5]);
                    unsigned H1 = pkbf(S[i0 + 6], S[i0 + 7]);
                    unsigned sel0 = hi ? L0 : H0;        // offer what partner needs
                    unsigned sel1 = hi ? L1 : H1;
                    unsigned x0 = __shfl_xor((int)sel0, 32, 64);
                    unsigned x1 = __shfl_xor((int)sel1, 32, 64);
                    uint4 f;
                    f.x = hi ? x0 : L0;
                    f.y = hi ? x1 : L1;
                    f.z = hi ? H0 : x0;
                    f.w = hi ? H1 : x1;
                    pf[wl] = __builtin_bit_cast(bf16x8, f);
                }
                __builtin_amdgcn_s_setprio(1);
                #pragma unroll
                for (int wl = 0; wl < 2; wl++)           // O^T += V^T P
                    #pragma unroll
                    for (int dt = 0; dt < 4; dt++) {
                        bf16x8 vf = *reinterpret_cast<const bf16x8*>(
                            vb + (dt * 32 + c) * 128 + ((vcol0 + wl * 32 + hi * 16) ^ vswz));
                        O[dt] = __builtin_amdgcn_mfma_f32_32x32x16_bf16(vf, pf[wl], O[dt], 0, 0, 0);
                    }
                __builtin_amdgcn_s_setprio(0);
            }
            __builtin_amdgcn_s_barrier();                // all waves done reading buf bi
            if (it + 2 < nIt) {                          // stage it+2 into freed buffer
                const char* Ks = Kb + (long)(it + 2) * 32768;
                const char* Vs = Vb + (long)(it + 2) * 32768;
                #pragma unroll
                for (int i = 0; i < 4; i++) {
                    gload16(Ks + kOff[i], kBuf + lOff[i]);
                    gload16(Vs + vOff[i], vBuf + lOff[i]);
                }
            }
        }

        l += __shfl_xor(l, 32, 64);                      // combine partner kv-reg halves

        if (kvq != 0) {                                  // quarters 1..3 publish partials
            const int sl = qs * 3 + (kvq - 1);
            char* om = smem + sl * 16384;
            #pragma unroll
            for (int dt = 0; dt < 4; dt++)
                #pragma unroll
                for (int g = 0; g < 4; g++) {
                    float4 w4 = { O[dt][4 * g + 0], O[dt][4 * g + 1],
                                  O[dt][4 * g + 2], O[dt][4 * g + 3] };
                    *reinterpret_cast<float4*>(
                        om + c * 512 + ((dt * 128 + g * 32 + hi * 16) ^ ((c & 7) << 4))) = w4;
                }
            if (hi == 0) { mlb[sl * 64 + c] = m; mlb[sl * 64 + 32 + c] = l; }
        }
        __syncthreads();
        if (kvq == 0) {                                  // quarter 0 merges + writes out
            float mq[3], lq[3];
            float mx = m;                                // kvq0 always has data (finite)
            #pragma unroll
            for (int p = 0; p < 3; p++) {
                const int sl = qs * 3 + p;
                mq[p] = mlb[sl * 64 + c];
                lq[p] = mlb[sl * 64 + 32 + c];
                mx = fmaxf(mx, mq[p]);
            }
            float f0 = __expf(m - mx);
            float lt = l * f0;
            float fq[3];
            #pragma unroll
            for (int p = 0; p < 3; p++) { fq[p] = __expf(mq[p] - mx); lt += lq[p] * fq[p]; }
            float linv = 1.0f / lt;
            #pragma unroll
            for (int dt = 0; dt < 4; dt++)
                #pragma unroll
                for (int g = 0; g < 4; g++) {
                    float4 r;
                    r.x = O[dt][4 * g + 0] * f0;
                    r.y = O[dt][4 * g + 1] * f0;
                    r.z = O[dt][4 * g + 2] * f0;
                    r.w = O[dt][4 * g + 3] * f0;
                    #pragma unroll
                    for (int p = 0; p < 3; p++) {
                        const char* om = smem + (qs * 3 + p) * 16384;
                        float4 o1 = *reinterpret_cast<const float4*>(
                            om + c * 512 + ((dt * 128 + g * 32 + hi * 16) ^ ((c & 7) << 4)));
                        r.x += o1.x * fq[p]; r.y += o1.y * fq[p];
                        r.z += o1.z * fq[p]; r.w += o1.w * fq[p];
                    }
                    r.x *= linv; r.y *= linv; r.z *= linv; r.w *= linv;
                    *reinterpret_cast<float4*>(
                        &out[base + (long)qa * 128 + dt * 32 + 8 * g + 4 * hi]) = r;
                }
        }
        __syncthreads();                                 // LDS safe before next phase stages
    }
}

extern "C" void kernel_launch(void* const* d_in, const int* in_sizes, int n_in,
                              void* d_out, int out_size, void* d_ws, size_t ws_size,
                              hipStream_t stream) {
    const float* x  = (const float*)d_in[0];
    const float* Wq = (const float*)d_in[1];
    const float* Wk = (const float*)d_in[2];
    const float* Wv = (const float*)d_in[3];
    float* out = (float*)d_out;
    bf16* Q   = (bf16*)d_ws;                      // [32768][128]
    bf16* K   = Q   + (size_t)32768 * 128;
    bf16* V   = K   + (size_t)32768 * 128;
    bf16* Wt  = V   + (size_t)32768 * 128;        // [3][128][1024]
    bf16* Vtt = Wt  + (size_t)3 * 128 * 1024;     // [8][64][128][64] tile-major
    wt_kernel<<<96, 256, 0, stream>>>(Wq, Wk, Wv, Wt);
    qkv_kernel<<<512, 512, 0, stream>>>(x, Wt, Q, K, V);
    vtrans_kernel<<<dim3(64, 8), 256, 0, stream>>>(V, Vtt);
    attn_kernel<<<256, 512, 0, stream>>>(Q, K, Vtt, out);
}

// Round 12
// 113.622 us; speedup vs baseline: 1.0420x; 1.0233x over previous
//
#include <hip/hip_runtime.h>
#include <hip/hip_bf16.h>

#define TB 8
#define TT 4096
#define TC 1024
#define THS 128

typedef __bf16 bf16;
typedef __attribute__((ext_vector_type(8))) __bf16 bf16x8;
typedef __attribute__((ext_vector_type(2))) __bf16 bf16x2;
typedef __attribute__((ext_vector_type(4))) float f32x4;
typedef __attribute__((ext_vector_type(16))) float f32x16;

__device__ __forceinline__ unsigned pkbf(float a, float b) {
    bf16x2 t = { (bf16)a, (bf16)b };
    return __builtin_bit_cast(unsigned, t);
}

__device__ __forceinline__ void gload16(const void* g, void* l) {
    __builtin_amdgcn_global_load_lds(
        (const __attribute__((address_space(1))) void*)g,
        (__attribute__((address_space(3))) void*)l, 16, 0, 0);
}

// ---- W cast+transpose via LDS tile: Wt[w][n][k] = bf16(W_w[k][n]) ----
__global__ __launch_bounds__(256) void wt_kernel(const float* __restrict__ Wq,
                                                 const float* __restrict__ Wk,
                                                 const float* __restrict__ Wv,
                                                 bf16* __restrict__ Wt) {
    __shared__ float tile[64][65];
    const int tid = threadIdx.x;
    const int idx = blockIdx.x;                  // 96 blocks: w*32 + kt*2 + ntb
    const int w = idx >> 5;
    const int kt = (idx & 31) >> 1, ntb = idx & 1;
    const int k0 = kt * 64, n0 = ntb * 64;
    const float* W = (w == 0) ? Wq : (w == 1) ? Wk : Wv;
    #pragma unroll
    for (int i = 0; i < 4; i++) {
        int r = (tid >> 4) + i * 16;
        int c4 = (tid & 15) * 4;
        float4 x4 = *reinterpret_cast<const float4*>(&W[(long)(k0 + r) * 128 + n0 + c4]);
        tile[r][c4 + 0] = x4.x; tile[r][c4 + 1] = x4.y;
        tile[r][c4 + 2] = x4.z; tile[r][c4 + 3] = x4.w;
    }
    __syncthreads();
    const int n = tid >> 2, kk = (tid & 3) * 16;
    bf16 o[16];
    #pragma unroll
    for (int j = 0; j < 16; j++) o[j] = (bf16)tile[kk + j][n];
    bf16* dst = &Wt[(long)((w << 7) + n0 + n) * 1024 + k0 + kk];
    *reinterpret_cast<bf16x8*>(dst)     = *reinterpret_cast<bf16x8*>(&o[0]);
    *reinterpret_cast<bf16x8*>(dst + 8) = *reinterpret_cast<bf16x8*>(&o[8]);
}

// ---- fused QKV projection + direct Vtt production ----
// Main loop identical to R11 (64-row M-tile, 2 blocks/CU, counted vmcnt(2)).
// Epilogue: each output (Q, K, V) is bounced through a 64x136 LDS tile and written
// coalesced (bf16x8 rows). V is written DIRECTLY as the tile-major transposed Vtt
// tile this block owns (M-tile == Vtt tile granularity), eliminating the separate
// vtrans kernel and the V global round-trip.
__global__ __launch_bounds__(512, 4) void qkv_kernel(const float* __restrict__ x,
                                                     const bf16* __restrict__ Wt,
                                                     bf16* __restrict__ Q,
                                                     bf16* __restrict__ K,
                                                     bf16* __restrict__ Vtt) {
    __shared__ __align__(1024) char smem[81920];     // x dbuf @0/16K, W @32K (48KB)
    const int tid = threadIdx.x;
    const int wave = tid >> 6, lane = tid & 63;
    const int lr = lane & 15, g = lane >> 4;
    const int qs = wave >> 2, ns = wave & 3;
    const long row0 = (long)blockIdx.x * 64;

    int xOff[2], xL[2];                              // x: 16KB, rows 256B, swz256
    #pragma unroll
    for (int i = 0; i < 2; i++) {
        int D = wave * 2048 + i * 1024 + lane * 16;
        int r = D >> 8, c = D & 255;
        xOff[i] = r * 4096 + (c ^ (((r & 7) << 4) ^ (((r >> 3) & 1) << 7)));
        xL[i] = wave * 2048 + i * 1024;
    }
    int wOff[6], wL[6];                              // W: 48KB, rows 128B, swz128
    #pragma unroll
    for (int i = 0; i < 6; i++) {
        int D = wave * 6144 + i * 1024 + lane * 16;
        int n = D >> 7, c = D & 127;
        wOff[i] = n * 2048 + (c ^ ((n & 7) << 4));
        wL[i] = wave * 6144 + i * 1024;
    }
    const char* xb = (const char*)x + row0 * 4096;
    const char* wb = (const char*)Wt;

    f32x4 acc[2][6] = {};

    {   // prologue: x(0), W(0), x(1)
        #pragma unroll
        for (int i = 0; i < 2; i++) gload16(xb + xOff[i], smem + xL[i]);
        #pragma unroll
        for (int i = 0; i < 6; i++) gload16(wb + wOff[i], smem + 32768 + wL[i]);
        #pragma unroll
        for (int i = 0; i < 2; i++) gload16(xb + 256 + xOff[i], smem + 16384 + xL[i]);
    }

    #pragma unroll 1
    for (int s = 0; s < 16; s++) {
        if (s < 15) asm volatile("s_waitcnt vmcnt(2)" ::: "memory");   // drain x(s),W(s); keep x(s+1)
        else        asm volatile("s_waitcnt vmcnt(0)" ::: "memory");
        __builtin_amdgcn_s_barrier();

        const char* xp = smem + (s & 1) * 16384;
        const char* wp = smem + 32768;
        bf16x8 a[2][2];
        #pragma unroll
        for (int ar = 0; ar < 2; ar++) {             // A-frags: f32 LDS -> bf16 regs
            const int r = qs * 32 + ar * 16 + lr;
            const int rs = ((r & 7) << 4) ^ (((r >> 3) & 1) << 7);
            #pragma unroll
            for (int ks = 0; ks < 2; ks++) {
                f32x4 lo  = *reinterpret_cast<const f32x4*>(xp + r * 256 + ((ks * 128 + g * 32) ^ rs));
                f32x4 hi4 = *reinterpret_cast<const f32x4*>(xp + r * 256 + ((ks * 128 + g * 32 + 16) ^ rs));
                uint4 u;
                u.x = pkbf(lo[0], lo[1]);  u.y = pkbf(lo[2], lo[3]);
                u.z = pkbf(hi4[0], hi4[1]); u.w = pkbf(hi4[2], hi4[3]);
                a[ar][ks] = __builtin_bit_cast(bf16x8, u);
            }
        }
        __builtin_amdgcn_s_setprio(1);
        #pragma unroll
        for (int nt = 0; nt < 6; nt++) {
            const int n = ns * 96 + nt * 16 + lr;
            const int nsw = (n & 7) << 4;
            #pragma unroll
            for (int ks = 0; ks < 2; ks++) {
                bf16x8 bfr = *reinterpret_cast<const bf16x8*>(wp + n * 128 + ((ks * 64 + g * 16) ^ nsw));
                #pragma unroll
                for (int ar = 0; ar < 2; ar++)
                    acc[ar][nt] = __builtin_amdgcn_mfma_f32_16x16x32_bf16(a[ar][ks], bfr, acc[ar][nt], 0, 0, 0);
            }
        }
        __builtin_amdgcn_s_setprio(0);
        __builtin_amdgcn_s_barrier();                // all waves done with x(s) buf + W

        if (s + 1 < 16) {                            // stage W(s+1) then x(s+2)
            #pragma unroll
            for (int i = 0; i < 6; i++)
                gload16(wb + (s + 1) * 128 + wOff[i], smem + 32768 + wL[i]);
        }
        if (s + 2 < 16) {
            #pragma unroll
            for (int i = 0; i < 2; i++)
                gload16(xb + (s + 2) * 256 + xOff[i], smem + (s & 1) * 16384 + xL[i]);
        }
    }

    // ---- epilogue: LDS-bounced, coalesced outputs; V written as transposed Vtt tile ----
    const float qscale = 0.08838834764831845f;       // 128^-0.5
    bf16* ld = (bf16*)smem;                          // [64][136] bf16 (17KB, main loop done)
    #pragma unroll 1
    for (int wsel = 0; wsel < 3; wsel++) {
        __syncthreads();                             // LDS free for this slice
        #pragma unroll
        for (int nt = 0; nt < 6; nt++) {
            const int colbase = ns * 96 + nt * 16;   // wave-uniform; 16-col frag never crosses 128
            if ((colbase >> 7) != wsel) continue;
            const int d = (colbase + lr) & 127;
            #pragma unroll
            for (int ar = 0; ar < 2; ar++)
                #pragma unroll
                for (int r = 0; r < 4; r++) {
                    float val = acc[ar][nt][r];
                    if (wsel == 0) val *= qscale;
                    const int lrow = qs * 32 + ar * 16 + g * 4 + r;
                    ld[lrow * 136 + d] = (bf16)val;
                }
        }
        __syncthreads();
        if (wsel < 2) {                              // Q/K: row-major, 16B/lane coalesced
            bf16* dst = (wsel == 0 ? Q : K) + row0 * 128;
            #pragma unroll
            for (int i = 0; i < 2; i++) {
                const int slot = tid + 512 * i;
                const int rr = slot >> 4, c8 = (slot & 15) * 8;
                bf16x8 vv = *reinterpret_cast<const bf16x8*>(&ld[rr * 136 + c8]);
                *reinterpret_cast<bf16x8*>(&dst[rr * 128 + c8]) = vv;
            }
        } else {                                     // V: transposed tile-major Vtt tile
            bf16* dst = Vtt + (long)blockIdx.x * 8192;   // [128][64] for this 64-row tile
            #pragma unroll
            for (int i = 0; i < 2; i++) {
                const int slot = tid + 512 * i;
                const int d = slot >> 3, t8 = (slot & 7) * 8;
                bf16x8 vv;
                #pragma unroll
                for (int j = 0; j < 8; j++) vv[j] = ld[(t8 + j) * 136 + d];
                *reinterpret_cast<bf16x8*>(&dst[d * 64 + t8]) = vv;
            }
        }
    }
}

// ---- causal flash attention (unchanged from R9) ----
__global__ __launch_bounds__(512, 2) void attn_kernel(const bf16* __restrict__ Q,
                                                      const bf16* __restrict__ K,
                                                      const bf16* __restrict__ Vtt,
                                                      float* __restrict__ out) {
    __shared__ __align__(1024) char smem[131072];        // kbuf[2]@0/32K, vbuf[2]@64K/96K
    __shared__ float mlb[6 * 64];
    const int tid = threadIdx.x;
    const int wave = tid >> 6, lane = tid & 63;
    const int c = lane & 31, hi = lane >> 5;
    const int qs = wave >> 2, kvq = wave & 3;
    const int kswz = ((c & 7) << 4) ^ (((c >> 3) & 1) << 7);
    const int vswz = (c & 7) << 4;
    const int v = blockIdx.x >> 3, b = blockIdx.x & 7;   // batch pinned to XCD
    const long base = (long)b * TT * 128;
    const char* Kb = (const char*)(K + base);
    const char* Vb = (const char*)Vtt + (long)b * (64 * 16384);

    int kOff[4], vOff[4], lOff[4];
    #pragma unroll
    for (int i = 0; i < 4; i++) {
        int D = wave * 4096 + i * 1024 + lane * 16;      // linear dest byte in 32KB
        kOff[i] = (D & ~255) | ((D & 255) ^ (((D >> 8) & 7) << 4) ^ (((D >> 11) & 1) << 7));
        vOff[i] = (D & ~127) | ((D & 127) ^ (((D >> 7) & 7) << 4));
        lOff[i] = wave * 4096 + i * 1024;                // HW adds lane*16
    }

    #pragma unroll 1
    for (int ph = 0; ph < 2; ph++) {
        const int qt = ph ? 63 - v : v;
        const int nIt = (qt + 2) >> 1;                   // ceil((qt+1)/2) KVB=128 tiles
        const int q0w = qt * 64 + qs * 32;
        const int qa = q0w + c;

        bf16x8 qf[8];
        #pragma unroll
        for (int dw = 0; dw < 8; dw++)
            qf[dw] = *reinterpret_cast<const bf16x8*>(&Q[base + (long)qa * 128 + dw * 16 + hi * 8]);

        f32x16 O[4] = {};
        float m = -__builtin_inff(), l = 0.f;

        {   // prologue: stage tiles 0 (and 1) -> stage-ahead-2
            #pragma unroll
            for (int i = 0; i < 4; i++) {
                gload16(Kb + kOff[i], smem + lOff[i]);
                gload16(Vb + vOff[i], smem + 65536 + lOff[i]);
            }
            if (nIt > 1) {
                #pragma unroll
                for (int i = 0; i < 4; i++) {
                    gload16(Kb + 32768 + kOff[i], smem + 32768 + lOff[i]);
                    gload16(Vb + 32768 + vOff[i], smem + 98304 + lOff[i]);
                }
            }
        }

        #pragma unroll 1
        for (int it = 0; it < nIt; it++) {
            const int bi = it & 1;
            char* kBuf = smem + bi * 32768;              // runtime-indexed (no const-init LDS ptr)
            char* vBuf = smem + 65536 + bi * 32768;
            if (it + 1 < nIt) asm volatile("s_waitcnt vmcnt(8)" ::: "memory");
            else              asm volatile("s_waitcnt vmcnt(0)" ::: "memory");
            __builtin_amdgcn_s_barrier();                // tile it visible to all waves

            const int kv0 = it * 128 + kvq * 32;
            if (kv0 <= q0w) {                            // 32-aligned => no empty q-rows
                const char* kb = kBuf + kvq * 8192;
                const char* vb = vBuf + (kvq >> 1) * 16384;
                const int vcol0 = (kvq & 1) * 64;        // byte offset of wave's 32 kv
                f32x16 S = {};
                __builtin_amdgcn_s_setprio(1);
                #pragma unroll
                for (int dw = 0; dw < 8; dw++) {         // S^T = K Q^T
                    bf16x8 kf = *reinterpret_cast<const bf16x8*>(
                        kb + c * 256 + ((dw * 32 + hi * 16) ^ kswz));
                    S = __builtin_amdgcn_mfma_f32_32x32x16_bf16(kf, qf[dw], S, 0, 0, 0);
                }
                __builtin_amdgcn_s_setprio(0);
                if (kv0 == q0w) {                        // diagonal tile: causal mask
                    #pragma unroll
                    for (int i = 0; i < 16; i++) {
                        int kvr = kv0 + (i & 3) + 8 * (i >> 2) + 4 * hi;
                        if (kvr > qa) S[i] = -__builtin_inff();
                    }
                }
                float t8[8];
                #pragma unroll
                for (int i = 0; i < 8; i++) t8[i] = fmaxf(S[i], S[i + 8]);
                float t4a = fmaxf(t8[0], t8[4]), t4b = fmaxf(t8[1], t8[5]);
                float t4c = fmaxf(t8[2], t8[6]), t4d = fmaxf(t8[3], t8[7]);
                float pm = fmaxf(fmaxf(t4a, t4b), fmaxf(t4c, t4d));
                pm = fmaxf(pm, __shfl_xor(pm, 32, 64));  // partner half (other 16 kv regs)
                if (!__all(pm - m <= 8.0f)) {            // defer-max
                    float mn = fmaxf(m, pm);
                    float fr = __expf(m - mn);
                    #pragma unroll
                    for (int dt = 0; dt < 4; dt++) O[dt] = O[dt] * fr;
                    l *= fr;
                    m = mn;
                }
                #pragma unroll
                for (int i = 0; i < 16; i++) S[i] = __expf(S[i] - m);
                float s8[8];
                #pragma unroll
                for (int i = 0; i < 8; i++) s8[i] = S[i] + S[i + 8];
                l += ((s8[0] + s8[4]) + (s8[1] + s8[5])) + ((s8[2] + s8[6]) + (s8[3] + s8[7]));

                bf16x8 pf[2];                            // P -> B-frags, sel-trick exchange
                #pragma unroll
                for (int wl = 0; wl < 2; wl++) {
                    const int i0 = 8 * wl;
                    unsigned L0 = pkbf(S[i0 + 0], S[i0 + 1]);
                    unsigned L1 = pkbf(S[i0 + 2], S[i0 + 3]);
                    unsigned H0 = pkbf(S[i0 + 4], S[i0 + 5]);
                    unsigned H1 = pkbf(S[i0 + 6], S[i0 + 7]);
                    unsigned sel0 = hi ? L0 : H0;        // offer what partner needs
                    unsigned sel1 = hi ? L1 : H1;
                    unsigned x0 = __shfl_xor((int)sel0, 32, 64);
                    unsigned x1 = __shfl_xor((int)sel1, 32, 64);
                    uint4 f;
                    f.x = hi ? x0 : L0;
                    f.y = hi ? x1 : L1;
                    f.z = hi ? H0 : x0;
                    f.w = hi ? H1 : x1;
                    pf[wl] = __builtin_bit_cast(bf16x8, f);
                }
                __builtin_amdgcn_s_setprio(1);
                #pragma unroll
                for (int wl = 0; wl < 2; wl++)           // O^T += V^T P
                    #pragma unroll
                    for (int dt = 0; dt < 4; dt++) {
                        bf16x8 vf = *reinterpret_cast<const bf16x8*>(
                            vb + (dt * 32 + c) * 128 + ((vcol0 + wl * 32 + hi * 16) ^ vswz));
                        O[dt] = __builtin_amdgcn_mfma_f32_32x32x16_bf16(vf, pf[wl], O[dt], 0, 0, 0);
                    }
                __builtin_amdgcn_s_setprio(0);
            }
            __builtin_amdgcn_s_barrier();                // all waves done reading buf bi
            if (it + 2 < nIt) {                          // stage it+2 into freed buffer
                const char* Ks = Kb + (long)(it + 2) * 32768;
                const char* Vs = Vb + (long)(it + 2) * 32768;
                #pragma unroll
                for (int i = 0; i < 4; i++) {
                    gload16(Ks + kOff[i], kBuf + lOff[i]);
                    gload16(Vs + vOff[i], vBuf + lOff[i]);
                }
            }
        }

        l += __shfl_xor(l, 32, 64);                      // combine partner kv-reg halves

        if (kvq != 0) {                                  // quarters 1..3 publish partials
            const int sl = qs * 3 + (kvq - 1);
            char* om = smem + sl * 16384;
            #pragma unroll
            for (int dt = 0; dt < 4; dt++)
                #pragma unroll
                for (int g = 0; g < 4; g++) {
                    float4 w4 = { O[dt][4 * g + 0], O[dt][4 * g + 1],
                                  O[dt][4 * g + 2], O[dt][4 * g + 3] };
                    *reinterpret_cast<float4*>(
                        om + c * 512 + ((dt * 128 + g * 32 + hi * 16) ^ ((c & 7) << 4))) = w4;
                }
            if (hi == 0) { mlb[sl * 64 + c] = m; mlb[sl * 64 + 32 + c] = l; }
        }
        __syncthreads();
        if (kvq == 0) {                                  // quarter 0 merges + writes out
            float mq[3], lq[3];
            float mx = m;                                // kvq0 always has data (finite)
            #pragma unroll
            for (int p = 0; p < 3; p++) {
                const int sl = qs * 3 + p;
                mq[p] = mlb[sl * 64 + c];
                lq[p] = mlb[sl * 64 + 32 + c];
                mx = fmaxf(mx, mq[p]);
            }
            float f0 = __expf(m - mx);
            float lt = l * f0;
            float fq[3];
            #pragma unroll
            for (int p = 0; p < 3; p++) { fq[p] = __expf(mq[p] - mx); lt += lq[p] * fq[p]; }
            float linv = 1.0f / lt;
            #pragma unroll
            for (int dt = 0; dt < 4; dt++)
                #pragma unroll
                for (int g = 0; g < 4; g++) {
                    float4 r;
                    r.x = O[dt][4 * g + 0] * f0;
                    r.y = O[dt][4 * g + 1] * f0;
                    r.z = O[dt][4 * g + 2] * f0;
                    r.w = O[dt][4 * g + 3] * f0;
                    #pragma unroll
                    for (int p = 0; p < 3; p++) {
                        const char* om = smem + (qs * 3 + p) * 16384;
                        float4 o1 = *reinterpret_cast<const float4*>(
                            om + c * 512 + ((dt * 128 + g * 32 + hi * 16) ^ ((c & 7) << 4)));
                        r.x += o1.x * fq[p]; r.y += o1.y * fq[p];
                        r.z += o1.z * fq[p]; r.w += o1.w * fq[p];
                    }
                    r.x *= linv; r.y *= linv; r.z *= linv; r.w *= linv;
                    *reinterpret_cast<float4*>(
                        &out[base + (long)qa * 128 + dt * 32 + 8 * g + 4 * hi]) = r;
                }
        }
        __syncthreads();                                 // LDS safe before next phase stages
    }
}

extern "C" void kernel_launch(void* const* d_in, const int* in_sizes, int n_in,
                              void* d_out, int out_size, void* d_ws, size_t ws_size,
                              hipStream_t stream) {
    const float* x  = (const float*)d_in[0];
    const float* Wq = (const float*)d_in[1];
    const float* Wk = (const float*)d_in[2];
    const float* Wv = (const float*)d_in[3];
    float* out = (float*)d_out;
    bf16* Q   = (bf16*)d_ws;                      // [32768][128]
    bf16* K   = Q   + (size_t)32768 * 128;
    bf16* Vtt = K   + (size_t)32768 * 128;        // [8][64][128][64] tile-major
    bf16* Wt  = Vtt + (size_t)8 * 64 * 128 * 64;  // [3][128][1024]
    wt_kernel<<<96, 256, 0, stream>>>(Wq, Wk, Wv, Wt);
    qkv_kernel<<<512, 512, 0, stream>>>(x, Wt, Q, K, Vtt);
    attn_kernel<<<256, 512, 0, stream>>>(Q, K, Vtt, out);
}